// Round 2
// baseline (745.234 us; speedup 1.0000x reference)
//
#include <hip/hip_runtime.h>
#include <math.h>

#define NC 37
#define NW 30

// Writes bias into every output slot (harness poisons d_out with 0xAA).
__global__ __launch_bounds__(256) void tide_init(float* __restrict__ out,
                                                 const float* __restrict__ bias,
                                                 int n) {
    int i = blockIdx.x * 256 + threadIdx.x;
    if (i < n) out[i] = bias[0];
}

// One 2->30->30(ReLU)->30(ReLU)->1 MLP evaluated for TWO batch points that
// share weights. Fully unrolled; all weight indices are wave-uniform
// (blockIdx-derived base + constant offsets) -> scalar loads + SGPR-operand
// v_fmac. Two independent FMA chains per weight amortize any load overhead.
__device__ __forceinline__ void mlp_eval2(
    float x00, float x01,      // batch point 0 inputs
    float x10, float x11,      // batch point 1 inputs
    const float* __restrict__ w1, const float* __restrict__ b1,
    const float* __restrict__ w2, const float* __restrict__ b2,
    const float* __restrict__ w3, const float* __restrict__ b3,
    const float* __restrict__ wo, float bo,
    float& r0, float& r1)
{
    float h0[NW], h1[NW];
    float g0[NW], g1[NW];

    // layer 1: Linear(2,30), NO ReLU (matches reference)
    #pragma unroll
    for (int o = 0; o < NW; ++o) {
        const float wa = w1[2*o], wb = w1[2*o+1], bb = b1[o];
        h0[o] = fmaf(wa, x00, fmaf(wb, x01, bb));
        h1[o] = fmaf(wa, x10, fmaf(wb, x11, bb));
    }

    // layer 2: Linear(30,30) + ReLU
    #pragma unroll
    for (int o = 0; o < NW; ++o) {
        float acc0 = b2[o], acc1 = acc0;
        #pragma unroll
        for (int i = 0; i < NW; ++i) {
            const float w = w2[o*NW + i];
            acc0 = fmaf(w, h0[i], acc0);
            acc1 = fmaf(w, h1[i], acc1);
        }
        g0[o] = fmaxf(acc0, 0.0f);
        g1[o] = fmaxf(acc1, 0.0f);
    }

    // layer 3: Linear(30,30) + ReLU
    #pragma unroll
    for (int o = 0; o < NW; ++o) {
        float acc0 = b3[o], acc1 = acc0;
        #pragma unroll
        for (int i = 0; i < NW; ++i) {
            const float w = w3[o*NW + i];
            acc0 = fmaf(w, g0[i], acc0);
            acc1 = fmaf(w, g1[i], acc1);
        }
        h0[o] = fmaxf(acc0, 0.0f);
        h1[o] = fmaxf(acc1, 0.0f);
    }

    // output layer: Linear(30,1)
    float s0 = bo, s1 = bo;
    #pragma unroll
    for (int i = 0; i < NW; ++i) {
        const float w = wo[i];
        s0 = fmaf(w, h0[i], s0);
        s1 = fmaf(w, h1[i], s1);
    }
    r0 = s0;
    r1 = s1;
}

__global__ __launch_bounds__(256, 2) void tide_main(
    const float* __restrict__ x, const float* __restrict__ a,
    const float* __restrict__ u, const float* __restrict__ f,
    const float* __restrict__ V, const float* __restrict__ t,
    const float* __restrict__ WH1, const float* __restrict__ bH1,
    const float* __restrict__ WH2, const float* __restrict__ bH2,
    const float* __restrict__ WH3, const float* __restrict__ bH3,
    const float* __restrict__ WHo, const float* __restrict__ bHo,
    const float* __restrict__ WP1, const float* __restrict__ bP1,
    const float* __restrict__ WP2, const float* __restrict__ bP2,
    const float* __restrict__ WP3, const float* __restrict__ bP3,
    const float* __restrict__ WPo, const float* __restrict__ bPo,
    float* __restrict__ out, int B)
{
    const int c  = blockIdx.y;
    const int b0 = blockIdx.x * 512 + threadIdx.x;   // lanes contiguous
    const int b1 = b0 + 256;                          // second contiguous slab
    if (b1 >= B + 256) return;                        // (B % 512 == 0 in practice)

    const bool ok0 = (b0 < B);
    const bool ok1 = (b1 < B);

    const float x00 = ok0 ? x[2*b0]     : 0.0f;
    const float x01 = ok0 ? x[2*b0 + 1] : 0.0f;
    const float x10 = ok1 ? x[2*b1]     : 0.0f;
    const float x11 = ok1 ? x[2*b1 + 1] : 0.0f;

    float H0, H1, p0, p1;
    mlp_eval2(x00, x01, x10, x11,
              WH1 + c*NW*2, bH1 + c*NW,
              WH2 + c*NW*NW, bH2 + c*NW,
              WH3 + c*NW*NW, bH3 + c*NW,
              WHo + c*NW, bHo[c], H0, H1);
    mlp_eval2(x00, x01, x10, x11,
              WP1 + c*NW*2, bP1 + c*NW,
              WP2 + c*NW*NW, bP2 + c*NW,
              WP3 + c*NW*NW, bP3 + c*NW,
              WPo + c*NW, bPo[c], p0, p1);

    if (ok0) {
        const long cb = (long)c * B + b0;
        const float phase = V[cb] + a[cb] * t[b0] + u[cb] - p0;
        atomicAdd(&out[b0], H0 * f[cb] * cosf(phase));
    }
    if (ok1) {
        const long cb = (long)c * B + b1;
        const float phase = V[cb] + a[cb] * t[b1] + u[cb] - p1;
        atomicAdd(&out[b1], H1 * f[cb] * cosf(phase));
    }
}

extern "C" void kernel_launch(void* const* d_in, const int* in_sizes, int n_in,
                              void* d_out, int out_size, void* d_ws, size_t ws_size,
                              hipStream_t stream) {
    const float* x    = (const float*)d_in[0];
    const float* a    = (const float*)d_in[1];
    const float* u    = (const float*)d_in[2];
    const float* f    = (const float*)d_in[3];
    const float* V    = (const float*)d_in[4];
    const float* t    = (const float*)d_in[5];
    const float* bias = (const float*)d_in[6];
    const float* WH1  = (const float*)d_in[7];
    const float* bH1  = (const float*)d_in[8];
    const float* WH2  = (const float*)d_in[9];
    const float* bH2  = (const float*)d_in[10];
    const float* WH3  = (const float*)d_in[11];
    const float* bH3  = (const float*)d_in[12];
    const float* WHo  = (const float*)d_in[13];
    const float* bHo  = (const float*)d_in[14];
    const float* WP1  = (const float*)d_in[15];
    const float* bP1  = (const float*)d_in[16];
    const float* WP2  = (const float*)d_in[17];
    const float* bP2  = (const float*)d_in[18];
    const float* WP3  = (const float*)d_in[19];
    const float* bP3  = (const float*)d_in[20];
    const float* WPo  = (const float*)d_in[21];
    const float* bPo  = (const float*)d_in[22];
    float* out = (float*)d_out;

    const int B = in_sizes[0] / 2;           // x is [B,2]

    // 1) out[b] = bias
    tide_init<<<(out_size + 255) / 256, 256, 0, stream>>>(out, bias, out_size);

    // 2) accumulate all 37 constituents; each thread does 2 batch points
    dim3 grid((B + 511) / 512, NC);
    tide_main<<<grid, 256, 0, stream>>>(x, a, u, f, V, t,
                                        WH1, bH1, WH2, bH2, WH3, bH3, WHo, bHo,
                                        WP1, bP1, WP2, bP2, WP3, bP3, WPo, bPo,
                                        out, B);
}

// Round 6
// 691.982 us; speedup vs baseline: 1.0770x; 1.0770x over previous
//
#include <hip/hip_runtime.h>
#include <math.h>

#define NC 37
#define NW 30

// -- force-unroll machinery: named scalars, zero runtime indexing ------------
#define REPEAT30(M) M(0) M(1) M(2) M(3) M(4) M(5) M(6) M(7) M(8) M(9) \
                    M(10) M(11) M(12) M(13) M(14) M(15) M(16) M(17) M(18) M(19) \
                    M(20) M(21) M(22) M(23) M(24) M(25) M(26) M(27) M(28) M(29)
#define REPEAT30P(M,o) M(o,0) M(o,1) M(o,2) M(o,3) M(o,4) M(o,5) M(o,6) M(o,7) \
                       M(o,8) M(o,9) M(o,10) M(o,11) M(o,12) M(o,13) M(o,14) M(o,15) \
                       M(o,16) M(o,17) M(o,18) M(o,19) M(o,20) M(o,21) M(o,22) M(o,23) \
                       M(o,24) M(o,25) M(o,26) M(o,27) M(o,28) M(o,29)

// Writes bias into every output slot (harness poisons d_out with 0xAA).
__global__ __launch_bounds__(256) void tide_init(float* __restrict__ out,
                                                 const float* __restrict__ bias,
                                                 int n) {
    int i = blockIdx.x * 256 + threadIdx.x;
    if (i < n) out[i] = bias[0];
}

// 2->30->30(ReLU)->30(ReLU)->1 MLP, one batch point, ALL activations as
// named scalar registers (h0..h29, g0..g29) -> guaranteed register
// allocation, zero scratch. Weight addresses are wave-uniform -> scalar
// loads (SGPR operands on v_fmac).
__device__ __forceinline__ float mlp_eval(
    float x0, float x1,
    const float* __restrict__ w1, const float* __restrict__ b1,
    const float* __restrict__ w2, const float* __restrict__ b2,
    const float* __restrict__ w3, const float* __restrict__ b3,
    const float* __restrict__ wo, float bo)
{
#define DECLH(i) float h##i;
    REPEAT30(DECLH)
#define DECLG(i) float g##i;
    REPEAT30(DECLG)

    // layer 1: Linear(2,30), NO ReLU (matches reference)
#define LAYER1(i) h##i = fmaf(w1[2*(i)], x0, fmaf(w1[2*(i)+1], x1, b1[(i)]));
    REPEAT30(LAYER1)

    // layer 2: Linear(30,30) + ReLU
#define FMA2(o,i) acc = fmaf(w2[(o)*NW+(i)], h##i, acc);
#define LAYER2(o) { float acc = b2[(o)]; REPEAT30P(FMA2,o) g##o = fmaxf(acc, 0.0f); }
    REPEAT30(LAYER2)

    // layer 3: Linear(30,30) + ReLU
#define FMA3(o,i) acc = fmaf(w3[(o)*NW+(i)], g##i, acc);
#define LAYER3(o) { float acc = b3[(o)]; REPEAT30P(FMA3,o) h##o = fmaxf(acc, 0.0f); }
    REPEAT30(LAYER3)

    // output layer: Linear(30,1)
    float r = bo;
#define OUTL(i) r = fmaf(wo[(i)], h##i, r);
    REPEAT30(OUTL)
    return r;

#undef DECLH
#undef DECLG
#undef LAYER1
#undef FMA2
#undef LAYER2
#undef FMA3
#undef LAYER3
#undef OUTL
}

// __launch_bounds__(256, 3): VGPR cap ~160. Deliberately NOT (256,4) — a
// 128-VGPR cap risks allocator-forced spills (the exact failure mode this
// rewrite fixes); 3 waves/SIMD is ample for straight-line FMA code.
__global__ __launch_bounds__(256, 3) void tide_main(
    const float* __restrict__ x, const float* __restrict__ a,
    const float* __restrict__ u, const float* __restrict__ f,
    const float* __restrict__ V, const float* __restrict__ t,
    const float* __restrict__ WH1, const float* __restrict__ bH1,
    const float* __restrict__ WH2, const float* __restrict__ bH2,
    const float* __restrict__ WH3, const float* __restrict__ bH3,
    const float* __restrict__ WHo, const float* __restrict__ bHo,
    const float* __restrict__ WP1, const float* __restrict__ bP1,
    const float* __restrict__ WP2, const float* __restrict__ bP2,
    const float* __restrict__ WP3, const float* __restrict__ bP3,
    const float* __restrict__ WPo, const float* __restrict__ bPo,
    float* __restrict__ out, int B)
{
    const int c = blockIdx.y;
    const int b = blockIdx.x * 256 + threadIdx.x;
    if (b >= B) return;

    const float x0 = x[2*b];
    const float x1 = x[2*b + 1];

    const float Hv = mlp_eval(x0, x1,
                              WH1 + c*NW*2, bH1 + c*NW,
                              WH2 + c*NW*NW, bH2 + c*NW,
                              WH3 + c*NW*NW, bH3 + c*NW,
                              WHo + c*NW, bHo[c]);
    const float pv = mlp_eval(x0, x1,
                              WP1 + c*NW*2, bP1 + c*NW,
                              WP2 + c*NW*NW, bP2 + c*NW,
                              WP3 + c*NW*NW, bP3 + c*NW,
                              WPo + c*NW, bPo[c]);

    const long cb = (long)c * B + b;
    const float phase = V[cb] + a[cb] * t[b] + u[cb] - pv;
    atomicAdd(&out[b], Hv * f[cb] * cosf(phase));
}

extern "C" void kernel_launch(void* const* d_in, const int* in_sizes, int n_in,
                              void* d_out, int out_size, void* d_ws, size_t ws_size,
                              hipStream_t stream) {
    const float* x    = (const float*)d_in[0];
    const float* a    = (const float*)d_in[1];
    const float* u    = (const float*)d_in[2];
    const float* f    = (const float*)d_in[3];
    const float* V    = (const float*)d_in[4];
    const float* t    = (const float*)d_in[5];
    const float* bias = (const float*)d_in[6];
    const float* WH1  = (const float*)d_in[7];
    const float* bH1  = (const float*)d_in[8];
    const float* WH2  = (const float*)d_in[9];
    const float* bH2  = (const float*)d_in[10];
    const float* WH3  = (const float*)d_in[11];
    const float* bH3  = (const float*)d_in[12];
    const float* WHo  = (const float*)d_in[13];
    const float* bHo  = (const float*)d_in[14];
    const float* WP1  = (const float*)d_in[15];
    const float* bP1  = (const float*)d_in[16];
    const float* WP2  = (const float*)d_in[17];
    const float* bP2  = (const float*)d_in[18];
    const float* WP3  = (const float*)d_in[19];
    const float* bP3  = (const float*)d_in[20];
    const float* WPo  = (const float*)d_in[21];
    const float* bPo  = (const float*)d_in[22];
    float* out = (float*)d_out;

    const int B = in_sizes[0] / 2;           // x is [B,2]

    // 1) out[b] = bias
    tide_init<<<(out_size + 255) / 256, 256, 0, stream>>>(out, bias, out_size);

    // 2) accumulate all 37 constituents, one (c,b) per thread
    dim3 grid((B + 255) / 256, NC);
    tide_main<<<grid, 256, 0, stream>>>(x, a, u, f, V, t,
                                        WH1, bH1, WH2, bH2, WH3, bH3, WHo, bHo,
                                        WP1, bP1, WP2, bP2, WP3, bP3, WPo, bPo,
                                        out, B);
}